// Round 2
// baseline (62.770 us; speedup 1.0000x reference)
//
#include <hip/hip_runtime.h>

// AUCM loss via moment expansion (round 2: coalesced, fewer moments).
//
// softplus(-d) on d in (-1,1):  ln2 - d/2 + d^2/8 - d^4/192 + d^6/2880
// (Taylor of log(2cosh(d/2)) - d/2; truncation error < 2.7e-5 on [-1,1],
//  threshold is 1.4e-2).
// Masked pairwise sum over (pos i, neg j) = binomial combination of power
// sums A_t = sum_{pos} p^t, N_t = sum_{neg} p^t = T_t - A_t, t = 0..6.
//
// k1: 16 blocks x 256 threads. Thread (c = tid&127, h = tid>>7) processes
// rows r = blk*64 + 2*i + h  -> each iteration the block's 256 loads span one
// contiguous 1KB line group (fully coalesced). Accumulates T_t (all rows) and
// P_t (pos rows) -- 14 registers. Pair-combine (t, t+128) via LDS, write
// moment-major partials to ws (coalesced across c).
// k2: one block combines 16 block-partials per class, binomial-combines to
// per-class mean + valid, reduces 128 classes to the scalar loss.

#define NM 7          // moments 0..6
#define NBLK 16       // k1 grid
#define LDS_STRIDE 15 // 14 payload + 1 pad (breaks 16-lane bank aliasing)

__global__ __launch_bounds__(256) void aucm_partials_kernel(
    const float* __restrict__ logits,
    const float* __restrict__ targets,
    float* __restrict__ ws,    // [2*NM][NBLK*128] moment-major partials
    int B, int C)
{
    const int tid = threadIdx.x;
    const int c   = tid & 127;
    const int h   = tid >> 7;          // 0 or 1
    const int rowsPerBlock = B / NBLK; // 64

    float T[NM], P[NM];
#pragma unroll
    for (int k = 0; k < NM; ++k) { T[k] = 0.0f; P[k] = 0.0f; }

    const int base = blockIdx.x * rowsPerBlock;
#pragma unroll 4
    for (int i = 0; i < rowsPerBlock / 2; ++i) {
        const int r = base + 2 * i + h;
        const float l  = logits[r * C + c];
        const float tg = targets[r * C + c];
        const float p  = 1.0f / (1.0f + __expf(-l));
        const float s  = (tg > 0.5f) ? 1.0f : 0.0f;
        float pw = 1.0f, pws = s;
#pragma unroll
        for (int k = 0; k < NM; ++k) {
            T[k] += pw;
            P[k] += pws;
            pw  *= p;
            pws *= p;
        }
    }

    // combine the two threads sharing class c (h=0 and h=1)
    __shared__ float red[128 * LDS_STRIDE];
    if (h == 1) {
#pragma unroll
        for (int k = 0; k < NM; ++k) {
            red[c * LDS_STRIDE + k]      = P[k];
            red[c * LDS_STRIDE + NM + k] = T[k];
        }
    }
    __syncthreads();
    if (h == 0) {
        const int pc = NBLK * 128;   // partial-column stride
#pragma unroll
        for (int k = 0; k < NM; ++k) {
            const float Pk = P[k] + red[c * LDS_STRIDE + k];
            const float Tk = T[k] + red[c * LDS_STRIDE + NM + k];
            ws[k * pc        + blockIdx.x * 128 + c] = Pk;
            ws[(NM + k) * pc + blockIdx.x * 128 + c] = Tk;
        }
    }
}

__global__ __launch_bounds__(256) void aucm_finalize_kernel(
    const float* __restrict__ ws, float* __restrict__ out)
{
    const int tid = threadIdx.x;
    const int c   = tid & 127;
    const int h   = tid >> 7;
    const int pc  = NBLK * 128;

    float M[2 * NM];
#pragma unroll
    for (int k = 0; k < 2 * NM; ++k) M[k] = 0.0f;
    // each thread sums half the blocks for its class (coalesced across c)
#pragma unroll
    for (int k = 0; k < 2 * NM; ++k) {
        float s = 0.0f;
#pragma unroll
        for (int b = 0; b < NBLK / 2; ++b)
            s += ws[k * pc + (h * (NBLK / 2) + b) * 128 + c];
        M[k] = s;
    }

    __shared__ float red[128 * LDS_STRIDE];
    if (h == 1) {
#pragma unroll
        for (int k = 0; k < 2 * NM; ++k) red[c * LDS_STRIDE + k] = M[k];
    }
    __syncthreads();

    float mean = 0.0f, validf = 0.0f;
    if (h == 0) {
        float A[NM], Nv[NM];
#pragma unroll
        for (int k = 0; k < NM; ++k) {
            const float Pk = M[k]      + red[c * LDS_STRIDE + k];
            const float Tk = M[NM + k] + red[c * LDS_STRIDE + NM + k];
            A[k]  = Pk;
            Nv[k] = Tk - Pk;
        }
        const float s1 = A[1]*Nv[0] - A[0]*Nv[1];
        const float s2 = A[2]*Nv[0] - 2.0f*A[1]*Nv[1] + A[0]*Nv[2];
        const float s4 = A[4]*Nv[0] - 4.0f*A[3]*Nv[1] + 6.0f*A[2]*Nv[2]
                       - 4.0f*A[1]*Nv[3] + A[0]*Nv[4];
        const float s6 = A[6]*Nv[0] - 6.0f*A[5]*Nv[1] + 15.0f*A[4]*Nv[2]
                       - 20.0f*A[3]*Nv[3] + 15.0f*A[2]*Nv[4] - 6.0f*A[1]*Nv[5]
                       + A[0]*Nv[6];
        const float cnt = A[0] * Nv[0];
        const float num = 0.69314718056f * cnt
                        - 0.5f           * s1
                        + 0.125f         * s2
                        - 5.20833333e-3f * s4    // 1/192
                        + 3.47222222e-4f * s6;   // 1/2880
        const bool valid = (cnt > 0.0f);
        mean   = valid ? num / fmaxf(cnt, 1.0f) : 0.0f;
        validf = valid ? 1.0f : 0.0f;
    }

    // reduce 128 (mean, valid) pairs: waves 0,1 hold them (h==0 threads)
#pragma unroll
    for (int off = 32; off > 0; off >>= 1) {
        mean   += __shfl_down(mean, off);
        validf += __shfl_down(validf, off);
    }
    __shared__ float sm[2], sv[2];
    const int lane = tid & 63, wave = tid >> 6;
    __syncthreads();   // reuse of red[] done; also orders sm/sv
    if (h == 0 && lane == 0) { sm[wave] = mean; sv[wave] = validf; }
    __syncthreads();
    if (tid == 0) {
        const float ms = sm[0] + sm[1];
        const float vs = sv[0] + sv[1];
        out[0] = (vs > 0.0f) ? ms / fmaxf(vs, 1.0f) : 0.0f;
    }
}

extern "C" void kernel_launch(void* const* d_in, const int* in_sizes, int n_in,
                              void* d_out, int out_size, void* d_ws, size_t ws_size,
                              hipStream_t stream) {
    const float* logits  = (const float*)d_in[0];
    const float* targets = (const float*)d_in[1];
    float* ws  = (float*)d_ws;
    float* out = (float*)d_out;

    const int C = 128;
    const int B = in_sizes[0] / C;   // 1024

    aucm_partials_kernel<<<NBLK, 256, 0, stream>>>(logits, targets, ws, B, C);
    aucm_finalize_kernel<<<1, 256, 0, stream>>>(ws, out);
}